// Round 9
// baseline (496.094 us; speedup 1.0000x reference)
//
#include <hip/hip_runtime.h>

#define D 64
#define K 1024
#define NROWS (32 * 4096)
#define NELEM (NROWS * D)
#define COMMIT 0.25f
#define QBLOCKS 4096

#define FOR16(M) M(0) M(1) M(2) M(3) M(4) M(5) M(6) M(7) \
                 M(8) M(9) M(10) M(11) M(12) M(13) M(14) M(15)

// Opaque-value fence: prevents mul+add contraction so we can reproduce
// numpy's exact f32 rounding sequence (fl(x*x) then separate adds).
static __device__ __forceinline__ float fence(float v) {
    asm("" : "+v"(v));
    return v;
}

// numpy pairwise_sum for n=64 (pointer form, used in enorm kernel only).
static __device__ __forceinline__ float np_sumsq64(const float* __restrict__ e) {
    float r[8];
#pragma unroll
    for (int j = 0; j < 8; ++j) r[j] = fence(e[j] * e[j]);
#pragma unroll
    for (int t = 1; t < 8; ++t)
#pragma unroll
        for (int j = 0; j < 8; ++j) r[j] = r[j] + fence(e[8 * t + j] * e[8 * t + j]);
    return ((r[0] + r[1]) + (r[2] + r[3])) + ((r[4] + r[5]) + (r[6] + r[7]));
}

// ---------------- Kernel 1: embedding norms + zero loss slot ----------------
__global__ void enorm_kernel(const float* __restrict__ emb,
                             float* __restrict__ enorm,
                             float* __restrict__ loss_slot) {
    int k = blockIdx.x * blockDim.x + threadIdx.x;
    if (k == 0) *loss_slot = 0.0f;
    if (k < K) enorm[k] = np_sumsq64(emb + k * D);
}

// ---------------- Kernel 2: role-swapped argmin, array-free hot loop --------
// R2-R8 lesson: local C arrays (e0[64]) are runtime-indexed at SROA time ->
// scratch, not VGPRs; every iteration re-read them through buffer_loads
// (VGPR=40..88, VALUBusy ~40%). Here the two embedding rows per lane are 32
// NAMED float4 SSA values (macro-unrolled, compile-time member access only)
// -- no alloca anywhere in the hot path, so the allocator must keep them in
// VGPRs. x-row stays on the scalar (s_load) path: wave-uniform address.
// Score chain bit-identical to the reference:
//   s_k = fl( fl(R + N_k) - 2*dot_k ),  dot = ascending-i FMA chain,
//   R = numpy pairwise sumsq. Scores > 0, so packed (bits(s)<<32|k) u64 min
//   == lexicographic (s,k) min == numpy first-index argmin.
__global__ __launch_bounds__(256, 2) void argmin_kernel(
    const float* __restrict__ x, const float* __restrict__ emb,
    const float* __restrict__ enorm, int* __restrict__ idx_i,
    float* __restrict__ idx_f) {
    const int l = threadIdx.x & 63;
    const int w = threadIdx.x >> 6;
    const int row_base =
        __builtin_amdgcn_readfirstlane(blockIdx.x * 128 + w * 32);

    // ---- prologue: R for row row_base+(l&31), bit-exact numpy chain ----
    const float4* __restrict__ xr4 =
        (const float4*)(x + (size_t)(row_base + (l & 31)) * D);
#define DECL_X(i) float4 X_##i = xr4[i];
    FOR16(DECL_X)
#undef DECL_X
    // accumulator j takes elements 8t+j ascending t; fl(x*x) fenced apart.
    float r0 = fence(X_0.x * X_0.x), r1 = fence(X_0.y * X_0.y),
          r2 = fence(X_0.z * X_0.z), r3 = fence(X_0.w * X_0.w),
          r4 = fence(X_1.x * X_1.x), r5 = fence(X_1.y * X_1.y),
          r6 = fence(X_1.z * X_1.z), r7 = fence(X_1.w * X_1.w);
#define SUMSQ_T(Qa, Qb)                                              \
    r0 = r0 + fence(Qa.x * Qa.x); r1 = r1 + fence(Qa.y * Qa.y);      \
    r2 = r2 + fence(Qa.z * Qa.z); r3 = r3 + fence(Qa.w * Qa.w);      \
    r4 = r4 + fence(Qb.x * Qb.x); r5 = r5 + fence(Qb.y * Qb.y);      \
    r6 = r6 + fence(Qb.z * Qb.z); r7 = r7 + fence(Qb.w * Qb.w);
    SUMSQ_T(X_2, X_3)   SUMSQ_T(X_4, X_5)   SUMSQ_T(X_6, X_7)
    SUMSQ_T(X_8, X_9)   SUMSQ_T(X_10, X_11) SUMSQ_T(X_12, X_13)
    SUMSQ_T(X_14, X_15)
#undef SUMSQ_T
    const float Rv = ((r0 + r1) + (r2 + r3)) + ((r4 + r5) + (r6 + r7));

    unsigned long long bestPk = ~0ULL;

    for (int gp = 0; gp < 8; ++gp) {
        const int k0 = gp * 128 + l;
        const int k1 = k0 + 64;
        const float4* __restrict__ e04 =
            (const float4*)(emb + ((size_t)k0 << 6));
        const float4* __restrict__ e14 =
            (const float4*)(emb + ((size_t)k1 << 6));
        // 32 named float4s = 128 floats, pure SSA -> VGPR-resident.
#define DECL_E(i) float4 E0_##i = e04[i]; float4 E1_##i = e14[i];
        FOR16(DECL_E)
#undef DECL_E
        const float n0 = enorm[k0];
        const float n1 = enorm[k1];

        for (int r = 0; r < 32; ++r) {
            // Wave-uniform address -> scalar s_loads feed v_fma directly.
            const float* __restrict__ xrow = x + (size_t)(row_base + r) * D;
            float a0 = 0.0f, a1 = 0.0f;
#define FMA_Q(i) {                                                          \
            float xv0 = xrow[4 * i + 0], xv1 = xrow[4 * i + 1],             \
                  xv2 = xrow[4 * i + 2], xv3 = xrow[4 * i + 3];             \
            a0 = __builtin_fmaf(xv0, E0_##i.x, a0);                         \
            a1 = __builtin_fmaf(xv0, E1_##i.x, a1);                         \
            a0 = __builtin_fmaf(xv1, E0_##i.y, a0);                         \
            a1 = __builtin_fmaf(xv1, E1_##i.y, a1);                         \
            a0 = __builtin_fmaf(xv2, E0_##i.z, a0);                         \
            a1 = __builtin_fmaf(xv2, E1_##i.z, a1);                         \
            a0 = __builtin_fmaf(xv3, E0_##i.w, a0);                         \
            a1 = __builtin_fmaf(xv3, E1_##i.w, a1); }
            FOR16(FMA_Q)
#undef FMA_Q
            float Rb = __shfl(Rv, r);
            float s0 = (Rb + n0) - 2.0f * a0;
            float s1 = (Rb + n1) - 2.0f * a1;
            // lane-local combine (k0 < k1: strict < keeps first index)
            float sL = s0;
            int kL = k0;
            if (s1 < sL) { sL = s1; kL = k1; }
            // cross-lane lexicographic min via packed u64 butterfly
            unsigned long long pk =
                ((unsigned long long)__float_as_uint(sL) << 32) |
                (unsigned int)kL;
#pragma unroll
            for (int off = 1; off < 64; off <<= 1) {
                unsigned long long po = __shfl_xor(pk, off);
                pk = po < pk ? po : pk;
            }
            // row r's running best lives in lane r
            if (l == r) bestPk = pk < bestPk ? pk : bestPk;
        }
    }
    if (l < 32) {
        int bk = (int)(bestPk & 0xffffffffu);
        idx_i[row_base + l] = bk;
        idx_f[row_base + l] = (float)bk;
    }
}

// ---------------- Kernel 3: gather + straight-through + loss ----------------
__global__ __launch_bounds__(256) void quant_loss_kernel(
    const float* __restrict__ x, const float* __restrict__ emb,
    const int* __restrict__ idx, float* __restrict__ out_q,
    float* __restrict__ loss_slot) {
    float lsum = 0.0f;
    for (int j = blockIdx.x * 256 + threadIdx.x; j < NELEM;
         j += QBLOCKS * 256) {
        int row = j >> 6;
        int d = j & 63;
        int k = idx[row];
        float xv = x[j];
        float ev = emb[(k << 6) + d];
        float diff = ev - xv;   // stop_gradient(quantized - inputs)
        out_q[j] = xv + diff;   // inputs + (quantized - inputs)
        lsum = __builtin_fmaf(diff, diff, lsum);
    }
#pragma unroll
    for (int o = 32; o > 0; o >>= 1) lsum += __shfl_xor(lsum, o);
    __shared__ float wsum[4];
    int wid = threadIdx.x >> 6;
    if ((threadIdx.x & 63) == 0) wsum[wid] = lsum;
    __syncthreads();
    if (threadIdx.x == 0) {
        float bsum = (wsum[0] + wsum[1]) + (wsum[2] + wsum[3]);
        // loss = (1 + commitment_cost) * mean(diff^2)
        atomicAdd(loss_slot, bsum * ((1.0f + COMMIT) / (float)NELEM));
    }
}

extern "C" void kernel_launch(void* const* d_in, const int* in_sizes, int n_in,
                              void* d_out, int out_size, void* d_ws,
                              size_t ws_size, hipStream_t stream) {
    const float* x = (const float*)d_in[0];    // [32,4096,64] f32
    const float* emb = (const float*)d_in[1];  // [1024,64] f32

    float* out = (float*)d_out;
    float* loss_slot = out;              // out[0]
    float* out_q = out + 1;              // out[1 .. 1+NELEM)
    float* idx_f = out + 1 + NELEM;      // indices as f32

    float* enorm = (float*)d_ws;                 // 4 KB
    int* idx_i = (int*)((char*)d_ws + 4096);     // 512 KB

    enorm_kernel<<<(K + 255) / 256, 256, 0, stream>>>(emb, enorm, loss_slot);
    argmin_kernel<<<NROWS / 128, 256, 0, stream>>>(x, emb, enorm, idx_i,
                                                   idx_f);
    quant_loss_kernel<<<QBLOCKS, 256, 0, stream>>>(x, emb, idx_i, out_q,
                                                   loss_slot);
}

// Round 10
// 231.642 us; speedup vs baseline: 2.1416x; 2.1416x over previous
//
#include <hip/hip_runtime.h>

#define D 64
#define K 1024
#define NROWS (32 * 4096)
#define NELEM (NROWS * D)
#define COMMIT 0.25f
#define QBLOCKS 4096
#define DELTA 1e-4f

typedef __attribute__((ext_vector_type(8))) short short8v;   // 8 bf16
typedef __attribute__((ext_vector_type(4))) float f32x4;

// Opaque-value fence: prevents mul+add contraction so we can reproduce
// numpy's exact f32 rounding sequence.
static __device__ __forceinline__ float fence(float v) {
    asm("" : "+v"(v));
    return v;
}

// f32 -> bf16 bits, round-to-nearest-even (finite inputs only).
static __device__ __forceinline__ unsigned short f2bf(float f) {
    unsigned u = __float_as_uint(f);
    return (unsigned short)((u + 0x7FFFu + ((u >> 16) & 1u)) >> 16);
}

// numpy pairwise_sum for n=64: 8 accumulators stride 8, then pairwise tree.
static __device__ __forceinline__ float np_sumsq64(const float* __restrict__ e) {
    float r[8];
#pragma unroll
    for (int j = 0; j < 8; ++j) r[j] = fence(e[j] * e[j]);
#pragma unroll
    for (int t = 1; t < 8; ++t)
#pragma unroll
        for (int j = 0; j < 8; ++j) r[j] = r[j] + fence(e[8 * t + j] * e[8 * t + j]);
    return ((r[0] + r[1]) + (r[2] + r[3])) + ((r[4] + r[5]) + (r[6] + r[7]));
}

// Bit-exact reference score: s = fl( fl(R+N) - 2*dot ), dot = ascending-i
// sequential FMA chain (validated absmax=0 in R2/R4/R8).
static __device__ __forceinline__ float exact_score(
    const float* __restrict__ xrow, const float* __restrict__ erow, float R,
    float N) {
    float a = 0.0f;
#pragma unroll
    for (int i = 0; i < D; ++i) a = __builtin_fmaf(xrow[i], erow[i], a);
    return (R + N) - 2.0f * a;
}

// ---------------- Kernel 1: embedding prep ----------------
// Per code: np-chain norm + bf16 hi/lo split rows; zero loss slot.
__global__ void prep_emb_kernel(const float* __restrict__ emb,
                                float* __restrict__ enorm,
                                unsigned short* __restrict__ e_hi,
                                unsigned short* __restrict__ e_lo,
                                float* __restrict__ loss_slot) {
    int k = blockIdx.x * blockDim.x + threadIdx.x;
    if (k == 0) *loss_slot = 0.0f;
    if (k >= K) return;
    enorm[k] = np_sumsq64(emb + k * D);
    const float* e = emb + k * D;
#pragma unroll
    for (int i = 0; i < D; ++i) {
        float v = e[i];
        unsigned short h = f2bf(v);
        float hf = __uint_as_float((unsigned)h << 16);
        e_hi[k * D + i] = h;
        e_lo[k * D + i] = f2bf(v - hf);  // v-hf exact (Sterbenz)
    }
}

// ---------------- Kernel 2: MFMA argmin + exact rescue ----------------
// Block = 64 rows, 4 waves; wave w scans codes [256w,256w+256).
// t_k = N_k - 2*dot via 3-product bf16 hi/lo MFMA (error ~1e-7 << the
// reference's own f32 quantization eta=7.6e-6). Reference argmin k* must
// satisfy t_{k*} <= t_min + 2*eta, so candidates = {t <= m* + DELTA}.
// Rows with 1 candidate (-97%): done. Multi-candidate rows: re-evaluate the
// bit-exact reference chain, lexicographic (s,k) min = np first-index.
__global__ __launch_bounds__(256, 1) void argmin_kernel(
    const float* __restrict__ x, const float* __restrict__ emb,
    const float* __restrict__ enorm, const unsigned short* __restrict__ e_hi,
    const unsigned short* __restrict__ e_lo, int* __restrict__ idx_i,
    float* __restrict__ idx_f) {
    const int l = threadIdx.x & 63;
    const int w = threadIdx.x >> 6;
    const int rowbase = blockIdx.x * 64;
    const int cbase = w * 256;

    __shared__ float Rlds[64];
    __shared__ float wmin[4][64];
    __shared__ float gmin[64];
    __shared__ int cnt[64];
    __shared__ int clist[64][8];

    // ---- A-fragments: x rows as bf16 hi/lo, built once, register-resident.
    // A layout (16x16x32): row = l&15, k = h*32 + (l>>4)*8 + i. Any per-lane
    // k-permutation is safe as long as A and B use the same one.
    short8v Ahi[4][2], Alo[4][2];
#pragma unroll
    for (int rt = 0; rt < 4; ++rt)
#pragma unroll
        for (int h = 0; h < 2; ++h) {
            const float* p = x + (size_t)(rowbase + rt * 16 + (l & 15)) * D +
                             h * 32 + (l >> 4) * 8;
            float4 q0 = *(const float4*)p;
            float4 q1 = *(const float4*)(p + 4);
            float f[8] = {q0.x, q0.y, q0.z, q0.w, q1.x, q1.y, q1.z, q1.w};
            short8v hi, lo;
#pragma unroll
            for (int i = 0; i < 8; ++i) {
                unsigned short hb = f2bf(f[i]);
                float hf = __uint_as_float((unsigned)hb << 16);
                hi[i] = (short)hb;
                lo[i] = (short)f2bf(f[i] - hf);
            }
            Ahi[rt][h] = hi;
            Alo[rt][h] = lo;
        }

    if (threadIdx.x < 64) {
        Rlds[threadIdx.x] = np_sumsq64(x + (size_t)(rowbase + threadIdx.x) * D);
        cnt[threadIdx.x] = 0;
    }

    float minv[4][4];
#pragma unroll
    for (int rt = 0; rt < 4; ++rt)
#pragma unroll
        for (int r = 0; r < 4; ++r) minv[rt][r] = 3.402823466e+38f;

    // ---------------- pass A: per-lane running min of t ----------------
    for (int nt = 0; nt < 16; ++nt) {
        const int code = cbase + nt * 16 + (l & 15);
        const int koff = (l >> 4) * 8;
        short8v Bhi0 = *(const short8v*)(e_hi + code * D + koff);
        short8v Bhi1 = *(const short8v*)(e_hi + code * D + 32 + koff);
        short8v Blo0 = *(const short8v*)(e_lo + code * D + koff);
        short8v Blo1 = *(const short8v*)(e_lo + code * D + 32 + koff);
        const float Nc = enorm[code];
#pragma unroll
        for (int rt = 0; rt < 4; ++rt) {
            f32x4 acc = {0.f, 0.f, 0.f, 0.f};
            acc = __builtin_amdgcn_mfma_f32_16x16x32_bf16(Ahi[rt][0], Bhi0, acc, 0, 0, 0);
            acc = __builtin_amdgcn_mfma_f32_16x16x32_bf16(Ahi[rt][1], Bhi1, acc, 0, 0, 0);
            acc = __builtin_amdgcn_mfma_f32_16x16x32_bf16(Ahi[rt][0], Blo0, acc, 0, 0, 0);
            acc = __builtin_amdgcn_mfma_f32_16x16x32_bf16(Ahi[rt][1], Blo1, acc, 0, 0, 0);
            acc = __builtin_amdgcn_mfma_f32_16x16x32_bf16(Alo[rt][0], Bhi0, acc, 0, 0, 0);
            acc = __builtin_amdgcn_mfma_f32_16x16x32_bf16(Alo[rt][1], Bhi1, acc, 0, 0, 0);
#pragma unroll
            for (int r = 0; r < 4; ++r) {
                float t = __builtin_fmaf(-2.0f, acc[r], Nc);
                minv[rt][r] = fminf(minv[rt][r], t);
            }
        }
    }

    // C/D layout: col = l&15 (code), row = (l>>4)*4 + r. Row r's 16 holders
    // are the contiguous 16-lane group; xor 1/2/4/8 stays inside it.
#pragma unroll
    for (int rt = 0; rt < 4; ++rt)
#pragma unroll
        for (int r = 0; r < 4; ++r) {
            float m = minv[rt][r];
            m = fminf(m, __shfl_xor(m, 1));
            m = fminf(m, __shfl_xor(m, 2));
            m = fminf(m, __shfl_xor(m, 4));
            m = fminf(m, __shfl_xor(m, 8));
            minv[rt][r] = m;
        }
    if ((l & 15) == 0) {
        const int g = l >> 4;
#pragma unroll
        for (int rt = 0; rt < 4; ++rt)
#pragma unroll
            for (int r = 0; r < 4; ++r)
                wmin[w][rt * 16 + g * 4 + r] = minv[rt][r];
    }
    __syncthreads();
    if (threadIdx.x < 64)
        gmin[threadIdx.x] =
            fminf(fminf(wmin[0][threadIdx.x], wmin[1][threadIdx.x]),
                  fminf(wmin[2][threadIdx.x], wmin[3][threadIdx.x]));
    __syncthreads();

    float thr[4][4];
#pragma unroll
    for (int rt = 0; rt < 4; ++rt)
#pragma unroll
        for (int r = 0; r < 4; ++r)
            thr[rt][r] = gmin[rt * 16 + (l >> 4) * 4 + r] + DELTA;

    // ---------------- pass B: identical recompute, collect candidates ------
    for (int nt = 0; nt < 16; ++nt) {
        const int code = cbase + nt * 16 + (l & 15);
        const int koff = (l >> 4) * 8;
        short8v Bhi0 = *(const short8v*)(e_hi + code * D + koff);
        short8v Bhi1 = *(const short8v*)(e_hi + code * D + 32 + koff);
        short8v Blo0 = *(const short8v*)(e_lo + code * D + koff);
        short8v Blo1 = *(const short8v*)(e_lo + code * D + 32 + koff);
        const float Nc = enorm[code];
#pragma unroll
        for (int rt = 0; rt < 4; ++rt) {
            f32x4 acc = {0.f, 0.f, 0.f, 0.f};
            acc = __builtin_amdgcn_mfma_f32_16x16x32_bf16(Ahi[rt][0], Bhi0, acc, 0, 0, 0);
            acc = __builtin_amdgcn_mfma_f32_16x16x32_bf16(Ahi[rt][1], Bhi1, acc, 0, 0, 0);
            acc = __builtin_amdgcn_mfma_f32_16x16x32_bf16(Ahi[rt][0], Blo0, acc, 0, 0, 0);
            acc = __builtin_amdgcn_mfma_f32_16x16x32_bf16(Ahi[rt][1], Blo1, acc, 0, 0, 0);
            acc = __builtin_amdgcn_mfma_f32_16x16x32_bf16(Alo[rt][0], Bhi0, acc, 0, 0, 0);
            acc = __builtin_amdgcn_mfma_f32_16x16x32_bf16(Alo[rt][1], Bhi1, acc, 0, 0, 0);
#pragma unroll
            for (int r = 0; r < 4; ++r) {
                float t = __builtin_fmaf(-2.0f, acc[r], Nc);
                if (t <= thr[rt][r]) {
                    int row = rt * 16 + (l >> 4) * 4 + r;
                    int pos = atomicAdd(&cnt[row], 1);
                    if (pos < 8) clist[row][pos] = code;
                }
            }
        }
    }
    __syncthreads();

    // ---------------- epilogue: select / rescue ----------------
    if (threadIdx.x < 64) {
        const int row = threadIdx.x;
        const int grow = rowbase + row;
        const int n = cnt[row];
        int bk;
        if (n == 1) {
            bk = clist[row][0];
        } else {
            const float R = Rlds[row];
            const float* xrow = x + (size_t)grow * D;
            float sb = 3.402823466e+38f;
            int kb = 0x7fffffff;
            if (n <= 8) {
                for (int i = 0; i < n; ++i) {
                    int c = clist[row][i];
                    float s = exact_score(xrow, emb + (size_t)c * D, R, enorm[c]);
                    if (s < sb || (s == sb && c < kb)) { sb = s; kb = c; }
                }
            } else {  // overflow fallback: exact scan (never expected)
                for (int c = 0; c < K; ++c) {
                    float s = exact_score(xrow, emb + (size_t)c * D, R, enorm[c]);
                    if (s < sb || (s == sb && c < kb)) { sb = s; kb = c; }
                }
            }
            bk = kb;
        }
        idx_i[grow] = bk;
        idx_f[grow] = (float)bk;
    }
}

// ---------------- Kernel 3: gather + straight-through + loss ----------------
__global__ __launch_bounds__(256) void quant_loss_kernel(
    const float* __restrict__ x, const float* __restrict__ emb,
    const int* __restrict__ idx, float* __restrict__ out_q,
    float* __restrict__ loss_slot) {
    float lsum = 0.0f;
    for (int j = blockIdx.x * 256 + threadIdx.x; j < NELEM;
         j += QBLOCKS * 256) {
        int row = j >> 6;
        int d = j & 63;
        int k = idx[row];
        float xv = x[j];
        float ev = emb[(k << 6) + d];
        float diff = ev - xv;   // stop_gradient(quantized - inputs)
        out_q[j] = xv + diff;   // inputs + (quantized - inputs)
        lsum = __builtin_fmaf(diff, diff, lsum);
    }
#pragma unroll
    for (int o = 32; o > 0; o >>= 1) lsum += __shfl_xor(lsum, o);
    __shared__ float wsum[4];
    int wid = threadIdx.x >> 6;
    if ((threadIdx.x & 63) == 0) wsum[wid] = lsum;
    __syncthreads();
    if (threadIdx.x == 0) {
        float bsum = (wsum[0] + wsum[1]) + (wsum[2] + wsum[3]);
        atomicAdd(loss_slot, bsum * ((1.0f + COMMIT) / (float)NELEM));
    }
}

extern "C" void kernel_launch(void* const* d_in, const int* in_sizes, int n_in,
                              void* d_out, int out_size, void* d_ws,
                              size_t ws_size, hipStream_t stream) {
    const float* x = (const float*)d_in[0];    // [32,4096,64] f32
    const float* emb = (const float*)d_in[1];  // [1024,64] f32

    float* out = (float*)d_out;
    float* loss_slot = out;              // out[0]
    float* out_q = out + 1;              // out[1 .. 1+NELEM)
    float* idx_f = out + 1 + NELEM;      // indices as f32

    // workspace layout (16B-aligned slabs)
    float* enorm = (float*)d_ws;                                   // 4 KB
    unsigned short* e_hi = (unsigned short*)((char*)d_ws + 4096);  // 128 KB
    unsigned short* e_lo = (unsigned short*)((char*)d_ws + 135168);// 128 KB
    int* idx_i = (int*)((char*)d_ws + 266240);                     // 512 KB

    prep_emb_kernel<<<(K + 255) / 256, 256, 0, stream>>>(emb, enorm, e_hi,
                                                         e_lo, loss_slot);
    argmin_kernel<<<NROWS / 64, 256, 0, stream>>>(x, emb, enorm, e_hi, e_lo,
                                                  idx_i, idx_f);
    quant_loss_kernel<<<QBLOCKS, 256, 0, stream>>>(x, emb, idx_i, out_q,
                                                   loss_slot);
}